// Round 18
// baseline (159.979 us; speedup 1.0000x reference)
//
#include <hip/hip_runtime.h>

// Fused double-softmax attention, fp32 in/out, f16 MFMA for QK^T and PV.
// B=4 H=8 S=1024 D=64. Outputs: context [B,H,S,D] then attn [B,H,S,S].
// R18 = R13 reshaped to NT=256 (4 waves): 3-4 independent blocks/CU for
// phase desynchronization. Phase C waves own full d-tiles -> no pair-combine,
// no fscr, barriers 5 -> 3. Same per-wave load/MFMA code as R13.
typedef _Float16 f16;
typedef _Float16 f16x8 __attribute__((ext_vector_type(8)));
typedef _Float16 f16x4 __attribute__((ext_vector_type(4)));
typedef float f32x4 __attribute__((ext_vector_type(4)));
typedef int   i32x4 __attribute__((ext_vector_type(4)));

constexpr int B_ = 4, H_ = 8, S_ = 1024, D_ = 64;
constexpr int BQ = 16;        // q rows per block
constexpr int NT = 256;       // 4 waves
constexpr int QH_LD = 72;     // Qh row stride in f16
constexpr int SC_LD = 1032;   // sch row stride in f16
constexpr float LOG2E = 1.44269504f;

__device__ __forceinline__ float wred(float v) {
#pragma unroll
  for (int off = 32; off > 0; off >>= 1) v += __shfl_xor(v, off);
  return v;
}

__global__ __launch_bounds__(NT)
void fused_attn(const float* __restrict__ Q, const float* __restrict__ K,
                const float* __restrict__ V, const int* __restrict__ mask,
                const float* __restrict__ adj, const float* __restrict__ dist,
                const float* __restrict__ cw, const float* __restrict__ cb,
                float* __restrict__ outC, float* __restrict__ outA)
{
  __shared__ __align__(16) f16 Qh[BQ * QH_LD];     // 2.3 KB
  __shared__ __align__(16) f16 sch[BQ * SC_LD];    // 33.0 KB
  __shared__ float rs1w[4][16];
  __shared__ float rinv2[BQ];

  const int tid = threadIdx.x;
  // bijective XCD swizzle: 2048 blocks = 8 XCDs x 256 (4 heads per XCD)
  const int sw = (blockIdx.x & 7) * 256 + (blockIdx.x >> 3);
  const int qt = sw & 63;
  const int bh = sw >> 6;
  const int q0 = qt * BQ;
  const int wv = tid >> 6;    // wave 0..3
  const int ln = tid & 63;
  const int lg = ln >> 4;     // lane group 0..3
  const int li = ln & 15;

  const float* Qp = Q + ((size_t)bh * S_ + q0) * D_;
  const float* Kp = K + (size_t)bh * S_ * D_;
  const float* Vp = V + (size_t)bh * S_ * D_;
  const size_t rb = ((size_t)bh * S_ + q0) * S_;

  // stage Q tile -> f16 (256 threads x 1 float4 = 16x64)
  {
    const int q = tid >> 4, c4 = (tid & 15) << 2;
    float4 v = *(const float4*)(Qp + q * D_ + c4);
    f16* d = &Qh[q * QH_LD + c4];
    d[0] = (f16)v.x; d[1] = (f16)v.y; d[2] = (f16)v.z; d[3] = (f16)v.w;
  }
  const float w0 = cw[0], w1 = cw[1], w2 = cw[2], bb = cb[0];
  __syncthreads();                                  // (1)

  // hoist Q fragments (A operand; lane li = q-row li, k = s*32 + lg*8)
  f16x8 aq0 = *(const f16x8*)&Qh[li * QH_LD + 0 * 32 + lg * 8];
  f16x8 aq1 = *(const f16x8*)&Qh[li * QH_LD + 1 * 32 + lg * 8];

  // ===== Phase A: UNMASKED e = exp(QK^T/8) via MFMA; K straight from global ==
  // 4 waves x 16 cols = 64 k per iteration; 16 iterations cover k=0..1023.
  const int n0 = wv * 16;
  float rs[4] = {0.f, 0.f, 0.f, 0.f};
#pragma unroll 2
  for (int c = 0; c < 16; ++c) {
    const int kg = c * 64 + n0 + li;
    const float* Kr = Kp + (size_t)kg * D_ + lg * 8;
    const float4 ka = *(const float4*)(Kr + 0);
    const float4 kb = *(const float4*)(Kr + 4);
    const float4 kc2 = *(const float4*)(Kr + 32);
    const float4 kd = *(const float4*)(Kr + 36);
    f16x8 b0, b1;
    b0[0] = (f16)ka.x; b0[1] = (f16)ka.y; b0[2] = (f16)ka.z; b0[3] = (f16)ka.w;
    b0[4] = (f16)kb.x; b0[5] = (f16)kb.y; b0[6] = (f16)kb.z; b0[7] = (f16)kb.w;
    b1[0] = (f16)kc2.x; b1[1] = (f16)kc2.y; b1[2] = (f16)kc2.z; b1[3] = (f16)kc2.w;
    b1[4] = (f16)kd.x; b1[5] = (f16)kd.y; b1[6] = (f16)kd.z; b1[7] = (f16)kd.w;
    f32x4 acc = {0.f, 0.f, 0.f, 0.f};
    acc = __builtin_amdgcn_mfma_f32_16x16x32_f16(aq0, b0, acc, 0, 0, 0);
    acc = __builtin_amdgcn_mfma_f32_16x16x32_f16(aq1, b1, acc, 0, 0, 0);
#pragma unroll
    for (int r = 0; r < 4; ++r) {            // D[m][n]: m=lg*4+r, n=li
      const int m = lg * 4 + r;
      const f16 ef = (f16)exp2f(acc[r] * (0.125f * LOG2E));
      sch[m * SC_LD + kg] = ef;
      rs[r] += (float)ef;                    // rounded full-row sum
    }
  }
#pragma unroll
  for (int r = 0; r < 4; ++r) {              // reduce over 16 lanes per group
    rs[r] += __shfl_xor(rs[r], 1); rs[r] += __shfl_xor(rs[r], 2);
    rs[r] += __shfl_xor(rs[r], 4); rs[r] += __shfl_xor(rs[r], 8);
  }
  if (li == 0) {
#pragma unroll
    for (int r = 0; r < 4; ++r) rs1w[wv][lg * 4 + r] = rs[r];
  }
  __syncthreads();                                  // (2) sch + rs1w visible

  // ===== Phase B: mask fold + conv-softmax; wave -> rows 4wv..4wv+3 ==========
#pragma unroll
  for (int rr = 0; rr < 4; ++rr) {
    const int q = 4 * wv + rr;
    const size_t base = rb + (size_t)q * S_;
    const int k0 = ln * 4;
    // batched NONTEMPORAL loads: 12 global + 4 LDS issued before any use
    const i32x4 mv0 = __builtin_nontemporal_load((const i32x4*)(mask + base + k0 + 0));
    const i32x4 mv1 = __builtin_nontemporal_load((const i32x4*)(mask + base + k0 + 256));
    const i32x4 mv2 = __builtin_nontemporal_load((const i32x4*)(mask + base + k0 + 512));
    const i32x4 mv3 = __builtin_nontemporal_load((const i32x4*)(mask + base + k0 + 768));
    const f32x4 dv0 = __builtin_nontemporal_load((const f32x4*)(dist + base + k0 + 0));
    const f32x4 dv1 = __builtin_nontemporal_load((const f32x4*)(dist + base + k0 + 256));
    const f32x4 dv2 = __builtin_nontemporal_load((const f32x4*)(dist + base + k0 + 512));
    const f32x4 dv3 = __builtin_nontemporal_load((const f32x4*)(dist + base + k0 + 768));
    const f32x4 av0 = __builtin_nontemporal_load((const f32x4*)(adj + base + k0 + 0));
    const f32x4 av1 = __builtin_nontemporal_load((const f32x4*)(adj + base + k0 + 256));
    const f32x4 av2 = __builtin_nontemporal_load((const f32x4*)(adj + base + k0 + 512));
    const f32x4 av3 = __builtin_nontemporal_load((const f32x4*)(adj + base + k0 + 768));
    const f16x4 ef0 = *(const f16x4*)&sch[q * SC_LD + k0 + 0];
    const f16x4 ef1 = *(const f16x4*)&sch[q * SC_LD + k0 + 256];
    const f16x4 ef2 = *(const f16x4*)&sch[q * SC_LD + k0 + 512];
    const f16x4 ef3 = *(const f16x4*)&sch[q * SC_LD + k0 + 768];
    __builtin_amdgcn_sched_barrier(0);
    // denominator correction from masked entries
    float corr =
        (mv0[0] ? (float)ef0[0] : 0.f) + (mv0[1] ? (float)ef0[1] : 0.f) +
        (mv0[2] ? (float)ef0[2] : 0.f) + (mv0[3] ? (float)ef0[3] : 0.f) +
        (mv1[0] ? (float)ef1[0] : 0.f) + (mv1[1] ? (float)ef1[1] : 0.f) +
        (mv1[2] ? (float)ef1[2] : 0.f) + (mv1[3] ? (float)ef1[3] : 0.f) +
        (mv2[0] ? (float)ef2[0] : 0.f) + (mv2[1] ? (float)ef2[1] : 0.f) +
        (mv2[2] ? (float)ef2[2] : 0.f) + (mv2[3] ? (float)ef2[3] : 0.f) +
        (mv3[0] ? (float)ef3[0] : 0.f) + (mv3[1] ? (float)ef3[1] : 0.f) +
        (mv3[2] ? (float)ef3[2] : 0.f) + (mv3[3] ? (float)ef3[3] : 0.f);
    float tq = 0.f;
#pragma unroll
    for (int w = 0; w < 4; ++w) tq += rs1w[w][q];   // uniform broadcast reads
    corr = wred(corr);
    const float i1 = 1.f / (tq - corr);
    const float W0 = w0 * i1 * LOG2E, W1 = w1 * LOG2E, W2 = w2 * LOG2E;
    const float BBL = bb * LOG2E;
    f16x4 af0, af1, af2, af3;
    float s2 = 0.f;
#define CSM(AF, MV, DV, AV, EF)                                               \
    {                                                                         \
      const float t0 = fmaf(W0, (float)EF[0], fmaf(W1, DV[0], fmaf(W2, AV[0], BBL))); \
      const float t1 = fmaf(W0, (float)EF[1], fmaf(W1, DV[1], fmaf(W2, AV[1], BBL))); \
      const float t2 = fmaf(W0, (float)EF[2], fmaf(W1, DV[2], fmaf(W2, AV[2], BBL))); \
      const float t3 = fmaf(W0, (float)EF[3], fmaf(W1, DV[3], fmaf(W2, AV[3], BBL))); \
      const float a0 = MV[0] ? 0.f : exp2f(t0);                               \
      const float a1 = MV[1] ? 0.f : exp2f(t1);                               \
      const float a2 = MV[2] ? 0.f : exp2f(t2);                               \
      const float a3 = MV[3] ? 0.f : exp2f(t3);                               \
      AF[0] = (f16)a0; AF[1] = (f16)a1; AF[2] = (f16)a2; AF[3] = (f16)a3;     \
      s2 += a0 + a1 + a2 + a3;                                                \
    }
    CSM(af0, mv0, dv0, av0, ef0)
    CSM(af1, mv1, dv1, av1, ef1)
    CSM(af2, mv2, dv2, av2, ef2)
    CSM(af3, mv3, dv3, av3, ef3)
#undef CSM
    *(f16x4*)&sch[q * SC_LD + k0 + 0]   = af0;
    *(f16x4*)&sch[q * SC_LD + k0 + 256] = af1;
    *(f16x4*)&sch[q * SC_LD + k0 + 512] = af2;
    *(f16x4*)&sch[q * SC_LD + k0 + 768] = af3;
    s2 = wred(s2);
    const float i2 = 1.f / s2;
    if (ln == 0) rinv2[q] = i2;
    f32x4 o;
    o[0] = (float)af0[0] * i2; o[1] = (float)af0[1] * i2;
    o[2] = (float)af0[2] * i2; o[3] = (float)af0[3] * i2;
    __builtin_nontemporal_store(o, (f32x4*)(outA + base + k0 + 0));
    o[0] = (float)af1[0] * i2; o[1] = (float)af1[1] * i2;
    o[2] = (float)af1[2] * i2; o[3] = (float)af1[3] * i2;
    __builtin_nontemporal_store(o, (f32x4*)(outA + base + k0 + 256));
    o[0] = (float)af2[0] * i2; o[1] = (float)af2[1] * i2;
    o[2] = (float)af2[2] * i2; o[3] = (float)af2[3] * i2;
    __builtin_nontemporal_store(o, (f32x4*)(outA + base + k0 + 512));
    o[0] = (float)af3[0] * i2; o[1] = (float)af3[1] * i2;
    o[2] = (float)af3[2] * i2; o[3] = (float)af3[3] * i2;
    __builtin_nontemporal_store(o, (f32x4*)(outA + base + k0 + 768));
  }
  __syncthreads();                                  // (3) sch aw + rinv2 visible

  // ===== Phase C: ctx = P(f16) x V(f16); wave wv owns d-tile wv (full k) =====
  const int d0 = wv * 16 + li;
  f32x4 cacc = {0.f, 0.f, 0.f, 0.f};
#pragma unroll 2
  for (int c = 0; c < 8; ++c) {
#pragma unroll
    for (int s = 0; s < 4; ++s) {
      const float* Vc = Vp + (size_t)(c * 128 + s * 32 + lg * 8) * D_ + d0;
      f16x8 bfr;
#pragma unroll
      for (int j = 0; j < 8; ++j) bfr[j] = (f16)Vc[(size_t)j * D_];
      f16x8 a = *(const f16x8*)&sch[li * SC_LD + c * 128 + s * 32 + lg * 8];
      cacc = __builtin_amdgcn_mfma_f32_16x16x32_f16(a, bfr, cacc, 0, 0, 0);
    }
  }
  // direct store: lane (lg,li) holds ctx rows lg*4+r, col d0
#pragma unroll
  for (int r = 0; r < 4; ++r) {
    const int m = lg * 4 + r;
    outC[((size_t)bh * S_ + q0 + m) * D_ + d0] = cacc[r] * rinv2[m];
  }
}

extern "C" void kernel_launch(void* const* d_in, const int* in_sizes, int n_in,
                              void* d_out, int out_size, void* d_ws, size_t ws_size,
                              hipStream_t stream) {
  const float* Q    = (const float*)d_in[0];
  const float* K    = (const float*)d_in[1];
  const float* V    = (const float*)d_in[2];
  const int*   mask = (const int*)  d_in[3];
  const float* adj  = (const float*)d_in[4];
  const float* dist = (const float*)d_in[5];
  const float* cw   = (const float*)d_in[6];
  const float* cb   = (const float*)d_in[7];

  float* outC = (float*)d_out;                                   // [B,H,S,D]
  float* outA = outC + (size_t)B_ * H_ * S_ * D_;                // [B,H,S,S]

  fused_attn<<<dim3(B_ * H_ * (S_ / BQ)), NT, 0, stream>>>(
      Q, K, V, mask, adj, dist, cw, cb, outC, outA);
}

// Round 19
// 125.489 us; speedup vs baseline: 1.2749x; 1.2749x over previous
//
#include <hip/hip_runtime.h>

// Fused double-softmax attention, fp32 in/out, f16 MFMA for QK^T and PV.
// B=4 H=8 S=1024 D=64. Outputs: context [B,H,S,D] then attn [B,H,S,S].
// R19 = R13 scaled to BQ=32 (8 waves, 1024 blocks): each K/V fragment feeds
// TWO independent MFMAs (q-groups 0-15 and 16-31) -> load-latency hits per
// output row halve, dual-stream ILP comes free, barriers per row halve.
typedef _Float16 f16;
typedef _Float16 f16x8 __attribute__((ext_vector_type(8)));
typedef _Float16 f16x4 __attribute__((ext_vector_type(4)));
typedef float f32x4 __attribute__((ext_vector_type(4)));
typedef int   i32x4 __attribute__((ext_vector_type(4)));

constexpr int B_ = 4, H_ = 8, S_ = 1024, D_ = 64;
constexpr int BQ = 32;        // q rows per block
constexpr int NT = 512;       // 8 waves
constexpr int KC = 128;       // k per chunk (8 waves x 16 cols)
constexpr int QH_LD = 72;     // Qh row stride in f16
constexpr int SC_LD = 1032;   // sch row stride in f16
constexpr float LOG2E = 1.44269504f;

__device__ __forceinline__ float wred(float v) {
#pragma unroll
  for (int off = 32; off > 0; off >>= 1) v += __shfl_xor(v, off);
  return v;
}

__global__ __launch_bounds__(NT)
void fused_attn(const float* __restrict__ Q, const float* __restrict__ K,
                const float* __restrict__ V, const int* __restrict__ mask,
                const float* __restrict__ adj, const float* __restrict__ dist,
                const float* __restrict__ cw, const float* __restrict__ cb,
                float* __restrict__ outC, float* __restrict__ outA)
{
  __shared__ __align__(16) f16 Qh[BQ * QH_LD];     // 4.6 KB
  __shared__ __align__(16) f16 sch[BQ * SC_LD];    // 66.0 KB (fscr alias later)
  __shared__ float rs1w[8][BQ];                    // 1 KB
  __shared__ float rinv2[BQ];

  const int tid = threadIdx.x;
  // bijective XCD swizzle: 1024 blocks = 8 XCDs x 128 (4 heads per XCD)
  const int sw = (blockIdx.x & 7) * 128 + (blockIdx.x >> 3);
  const int qt = sw & 31;
  const int bh = sw >> 5;
  const int q0 = qt * BQ;
  const int wv = tid >> 6;    // wave 0..7
  const int ln = tid & 63;
  const int lg = ln >> 4;     // lane group 0..3
  const int li = ln & 15;

  const float* Qp = Q + ((size_t)bh * S_ + q0) * D_;
  const float* Kp = K + (size_t)bh * S_ * D_;
  const float* Vp = V + (size_t)bh * S_ * D_;
  const size_t rb = ((size_t)bh * S_ + q0) * S_;

  // stage Q tile -> f16 (512 threads x 1 float4 = 32x64)
  {
    const int q = tid >> 4, c4 = (tid & 15) << 2;
    float4 v = *(const float4*)(Qp + q * D_ + c4);
    f16* d = &Qh[q * QH_LD + c4];
    d[0] = (f16)v.x; d[1] = (f16)v.y; d[2] = (f16)v.z; d[3] = (f16)v.w;
  }
  const float w0 = cw[0], w1 = cw[1], w2 = cw[2], bb = cb[0];
  __syncthreads();                                  // (1)

  // Q fragments for BOTH q-groups (lane li = row g*16+li, k = s*32+lg*8)
  f16x8 aq00 = *(const f16x8*)&Qh[li * QH_LD + 0 * 32 + lg * 8];
  f16x8 aq01 = *(const f16x8*)&Qh[li * QH_LD + 1 * 32 + lg * 8];
  f16x8 aq10 = *(const f16x8*)&Qh[(16 + li) * QH_LD + 0 * 32 + lg * 8];
  f16x8 aq11 = *(const f16x8*)&Qh[(16 + li) * QH_LD + 1 * 32 + lg * 8];

  // ===== Phase A: e = exp(QK^T/8); each K fragment feeds 2 MFMAs =============
  const int n0 = wv * 16;
  float rs0[4] = {0.f, 0.f, 0.f, 0.f};
  float rs1[4] = {0.f, 0.f, 0.f, 0.f};
#pragma unroll 2
  for (int c = 0; c < 8; ++c) {
    const int kg = c * KC + n0 + li;
    const float* Kr = Kp + (size_t)kg * D_ + lg * 8;
    const float4 ka = *(const float4*)(Kr + 0);
    const float4 kb = *(const float4*)(Kr + 4);
    const float4 kc2 = *(const float4*)(Kr + 32);
    const float4 kd = *(const float4*)(Kr + 36);
    f16x8 b0, b1;
    b0[0] = (f16)ka.x; b0[1] = (f16)ka.y; b0[2] = (f16)ka.z; b0[3] = (f16)ka.w;
    b0[4] = (f16)kb.x; b0[5] = (f16)kb.y; b0[6] = (f16)kb.z; b0[7] = (f16)kb.w;
    b1[0] = (f16)kc2.x; b1[1] = (f16)kc2.y; b1[2] = (f16)kc2.z; b1[3] = (f16)kc2.w;
    b1[4] = (f16)kd.x; b1[5] = (f16)kd.y; b1[6] = (f16)kd.z; b1[7] = (f16)kd.w;
    f32x4 acc0 = {0.f, 0.f, 0.f, 0.f};
    f32x4 acc1 = {0.f, 0.f, 0.f, 0.f};
    acc0 = __builtin_amdgcn_mfma_f32_16x16x32_f16(aq00, b0, acc0, 0, 0, 0);
    acc1 = __builtin_amdgcn_mfma_f32_16x16x32_f16(aq10, b0, acc1, 0, 0, 0);
    acc0 = __builtin_amdgcn_mfma_f32_16x16x32_f16(aq01, b1, acc0, 0, 0, 0);
    acc1 = __builtin_amdgcn_mfma_f32_16x16x32_f16(aq11, b1, acc1, 0, 0, 0);
#pragma unroll
    for (int r = 0; r < 4; ++r) {            // D[m][n]: m=lg*4+r, n=li
      const int m = lg * 4 + r;
      const f16 e0 = (f16)exp2f(acc0[r] * (0.125f * LOG2E));
      const f16 e1 = (f16)exp2f(acc1[r] * (0.125f * LOG2E));
      sch[m * SC_LD + kg] = e0;
      sch[(16 + m) * SC_LD + kg] = e1;
      rs0[r] += (float)e0;
      rs1[r] += (float)e1;
    }
  }
#pragma unroll
  for (int r = 0; r < 4; ++r) {              // reduce over 16 lanes per group
    rs0[r] += __shfl_xor(rs0[r], 1); rs0[r] += __shfl_xor(rs0[r], 2);
    rs0[r] += __shfl_xor(rs0[r], 4); rs0[r] += __shfl_xor(rs0[r], 8);
    rs1[r] += __shfl_xor(rs1[r], 1); rs1[r] += __shfl_xor(rs1[r], 2);
    rs1[r] += __shfl_xor(rs1[r], 4); rs1[r] += __shfl_xor(rs1[r], 8);
  }
  if (li == 0) {
#pragma unroll
    for (int r = 0; r < 4; ++r) {
      rs1w[wv][lg * 4 + r] = rs0[r];
      rs1w[wv][16 + lg * 4 + r] = rs1[r];
    }
  }
  __syncthreads();                                  // (2) sch + rs1w visible

  // ===== Phase B: mask fold + conv-softmax; wave -> rows 4wv..4wv+3 ==========
#pragma unroll
  for (int rr = 0; rr < 4; ++rr) {
    const int q = 4 * wv + rr;
    const size_t base = rb + (size_t)q * S_;
    const int k0 = ln * 4;
    // batched NONTEMPORAL loads: 12 global + 4 LDS issued before any use
    const i32x4 mv0 = __builtin_nontemporal_load((const i32x4*)(mask + base + k0 + 0));
    const i32x4 mv1 = __builtin_nontemporal_load((const i32x4*)(mask + base + k0 + 256));
    const i32x4 mv2 = __builtin_nontemporal_load((const i32x4*)(mask + base + k0 + 512));
    const i32x4 mv3 = __builtin_nontemporal_load((const i32x4*)(mask + base + k0 + 768));
    const f32x4 dv0 = __builtin_nontemporal_load((const f32x4*)(dist + base + k0 + 0));
    const f32x4 dv1 = __builtin_nontemporal_load((const f32x4*)(dist + base + k0 + 256));
    const f32x4 dv2 = __builtin_nontemporal_load((const f32x4*)(dist + base + k0 + 512));
    const f32x4 dv3 = __builtin_nontemporal_load((const f32x4*)(dist + base + k0 + 768));
    const f32x4 av0 = __builtin_nontemporal_load((const f32x4*)(adj + base + k0 + 0));
    const f32x4 av1 = __builtin_nontemporal_load((const f32x4*)(adj + base + k0 + 256));
    const f32x4 av2 = __builtin_nontemporal_load((const f32x4*)(adj + base + k0 + 512));
    const f32x4 av3 = __builtin_nontemporal_load((const f32x4*)(adj + base + k0 + 768));
    const f16x4 ef0 = *(const f16x4*)&sch[q * SC_LD + k0 + 0];
    const f16x4 ef1 = *(const f16x4*)&sch[q * SC_LD + k0 + 256];
    const f16x4 ef2 = *(const f16x4*)&sch[q * SC_LD + k0 + 512];
    const f16x4 ef3 = *(const f16x4*)&sch[q * SC_LD + k0 + 768];
    __builtin_amdgcn_sched_barrier(0);
    // denominator correction from masked entries
    float corr =
        (mv0[0] ? (float)ef0[0] : 0.f) + (mv0[1] ? (float)ef0[1] : 0.f) +
        (mv0[2] ? (float)ef0[2] : 0.f) + (mv0[3] ? (float)ef0[3] : 0.f) +
        (mv1[0] ? (float)ef1[0] : 0.f) + (mv1[1] ? (float)ef1[1] : 0.f) +
        (mv1[2] ? (float)ef1[2] : 0.f) + (mv1[3] ? (float)ef1[3] : 0.f) +
        (mv2[0] ? (float)ef2[0] : 0.f) + (mv2[1] ? (float)ef2[1] : 0.f) +
        (mv2[2] ? (float)ef2[2] : 0.f) + (mv2[3] ? (float)ef2[3] : 0.f) +
        (mv3[0] ? (float)ef3[0] : 0.f) + (mv3[1] ? (float)ef3[1] : 0.f) +
        (mv3[2] ? (float)ef3[2] : 0.f) + (mv3[3] ? (float)ef3[3] : 0.f);
    float tq = 0.f;
#pragma unroll
    for (int w = 0; w < 8; ++w) tq += rs1w[w][q];   // uniform broadcast reads
    corr = wred(corr);
    const float i1 = 1.f / (tq - corr);
    const float W0 = w0 * i1 * LOG2E, W1 = w1 * LOG2E, W2 = w2 * LOG2E;
    const float BBL = bb * LOG2E;
    f16x4 af0, af1, af2, af3;
    float s2 = 0.f;
#define CSM(AF, MV, DV, AV, EF)                                               \
    {                                                                         \
      const float t0 = fmaf(W0, (float)EF[0], fmaf(W1, DV[0], fmaf(W2, AV[0], BBL))); \
      const float t1 = fmaf(W0, (float)EF[1], fmaf(W1, DV[1], fmaf(W2, AV[1], BBL))); \
      const float t2 = fmaf(W0, (float)EF[2], fmaf(W1, DV[2], fmaf(W2, AV[2], BBL))); \
      const float t3 = fmaf(W0, (float)EF[3], fmaf(W1, DV[3], fmaf(W2, AV[3], BBL))); \
      const float a0 = MV[0] ? 0.f : exp2f(t0);                               \
      const float a1 = MV[1] ? 0.f : exp2f(t1);                               \
      const float a2 = MV[2] ? 0.f : exp2f(t2);                               \
      const float a3 = MV[3] ? 0.f : exp2f(t3);                               \
      AF[0] = (f16)a0; AF[1] = (f16)a1; AF[2] = (f16)a2; AF[3] = (f16)a3;     \
      s2 += a0 + a1 + a2 + a3;                                                \
    }
    CSM(af0, mv0, dv0, av0, ef0)
    CSM(af1, mv1, dv1, av1, ef1)
    CSM(af2, mv2, dv2, av2, ef2)
    CSM(af3, mv3, dv3, av3, ef3)
#undef CSM
    *(f16x4*)&sch[q * SC_LD + k0 + 0]   = af0;
    *(f16x4*)&sch[q * SC_LD + k0 + 256] = af1;
    *(f16x4*)&sch[q * SC_LD + k0 + 512] = af2;
    *(f16x4*)&sch[q * SC_LD + k0 + 768] = af3;
    s2 = wred(s2);
    const float i2 = 1.f / s2;
    if (ln == 0) rinv2[q] = i2;
    f32x4 o;
    o[0] = (float)af0[0] * i2; o[1] = (float)af0[1] * i2;
    o[2] = (float)af0[2] * i2; o[3] = (float)af0[3] * i2;
    __builtin_nontemporal_store(o, (f32x4*)(outA + base + k0 + 0));
    o[0] = (float)af1[0] * i2; o[1] = (float)af1[1] * i2;
    o[2] = (float)af1[2] * i2; o[3] = (float)af1[3] * i2;
    __builtin_nontemporal_store(o, (f32x4*)(outA + base + k0 + 256));
    o[0] = (float)af2[0] * i2; o[1] = (float)af2[1] * i2;
    o[2] = (float)af2[2] * i2; o[3] = (float)af2[3] * i2;
    __builtin_nontemporal_store(o, (f32x4*)(outA + base + k0 + 512));
    o[0] = (float)af3[0] * i2; o[1] = (float)af3[1] * i2;
    o[2] = (float)af3[2] * i2; o[3] = (float)af3[3] * i2;
    __builtin_nontemporal_store(o, (f32x4*)(outA + base + k0 + 768));
  }
  __syncthreads();                                  // (3) sch aw-values visible

  // ===== Phase C: ctx = P(f16) x V(f16); V frag shared by both q-groups ======
  // wave wv: d-tile dt = wv&3, k-half kh = wv>>2 (k in [512kh, 512kh+512)).
  const int dt = wv & 3;
  const int kh = wv >> 2;
  const int d0 = dt * 16 + li;
  f32x4 c0 = {0.f, 0.f, 0.f, 0.f};
  f32x4 c1 = {0.f, 0.f, 0.f, 0.f};
#pragma unroll 2
  for (int c = 0; c < 4; ++c) {
#pragma unroll
    for (int s = 0; s < 4; ++s) {
      const int kbase = kh * 512 + c * 128 + s * 32;
      const float* Vc = Vp + (size_t)(kbase + lg * 8) * D_ + d0;
      f16x8 bfr;
#pragma unroll
      for (int j = 0; j < 8; ++j) bfr[j] = (f16)Vc[(size_t)j * D_];
      f16x8 a0 = *(const f16x8*)&sch[li * SC_LD + kbase + lg * 8];
      f16x8 a1 = *(const f16x8*)&sch[(16 + li) * SC_LD + kbase + lg * 8];
      c0 = __builtin_amdgcn_mfma_f32_16x16x32_f16(a0, bfr, c0, 0, 0, 0);
      c1 = __builtin_amdgcn_mfma_f32_16x16x32_f16(a1, bfr, c1, 0, 0, 0);
    }
  }
  __syncthreads();                                  // (4) all sch reads done
  float* fscr = reinterpret_cast<float*>(sch);      // 16 KB scratch alias
  *(f32x4*)&fscr[(wv * 64 + ln) * 8 + 0] = c0;
  *(f32x4*)&fscr[(wv * 64 + ln) * 8 + 4] = c1;
  __syncthreads();                                  // (5)
  if (tid < 256) {                    // combine k-halves, scale, write ctx
    const int t = tid >> 6, l2 = tid & 63;          // t = d-tile
    const int g2 = l2 >> 4, n = l2 & 15;
#pragma unroll
    for (int g = 0; g < 2; ++g) {
      f32x4 p  = *(const f32x4*)&fscr[((t) * 64 + l2) * 8 + 4 * g];
      f32x4 p2 = *(const f32x4*)&fscr[((t + 4) * 64 + l2) * 8 + 4 * g];
#pragma unroll
      for (int r = 0; r < 4; ++r) {
        const int m = g * 16 + g2 * 4 + r;
        outC[((size_t)bh * S_ + q0 + m) * D_ + t * 16 + n] =
            (p[r] + p2[r]) * rinv2[m];
      }
    }
  }
}

extern "C" void kernel_launch(void* const* d_in, const int* in_sizes, int n_in,
                              void* d_out, int out_size, void* d_ws, size_t ws_size,
                              hipStream_t stream) {
  const float* Q    = (const float*)d_in[0];
  const float* K    = (const float*)d_in[1];
  const float* V    = (const float*)d_in[2];
  const int*   mask = (const int*)  d_in[3];
  const float* adj  = (const float*)d_in[4];
  const float* dist = (const float*)d_in[5];
  const float* cw   = (const float*)d_in[6];
  const float* cb   = (const float*)d_in[7];

  float* outC = (float*)d_out;                                   // [B,H,S,D]
  float* outA = outC + (size_t)B_ * H_ * S_ * D_;                // [B,H,S,S]

  fused_attn<<<dim3(B_ * H_ * (S_ / BQ)), NT, 0, stream>>>(
      Q, K, V, mask, adj, dist, cw, cb, outC, outA);
}